// Round 23
// baseline (1302.686 us; speedup 1.0000x reference)
//
#include <hip/hip_runtime.h>

#define T_STEPS 2048
#define NBATCH  1024
#define L2E     1.442695040888963f

typedef _Float16 f16x8 __attribute__((ext_vector_type(8)));
typedef float    f32x4 __attribute__((ext_vector_type(4)));

// pack 2 floats -> 2 fp16 (RTZ) as one u32
__device__ __forceinline__ unsigned pk2(float a, float b) {
    auto v = __builtin_amdgcn_cvt_pkrtz(a, b);
    return __builtin_bit_cast(unsigned, v);
}

// load 8 consecutive fp32 -> 8 fp16 (RNE) fragment
__device__ __forceinline__ f16x8 loadrow8(const float* p) {
    float4 lo = *reinterpret_cast<const float4*>(p);
    float4 hi = *reinterpret_cast<const float4*>(p + 4);
    f16x8 r;
    r[0] = (_Float16)lo.x; r[1] = (_Float16)lo.y;
    r[2] = (_Float16)lo.z; r[3] = (_Float16)lo.w;
    r[4] = (_Float16)hi.x; r[5] = (_Float16)hi.y;
    r[6] = (_Float16)hi.z; r[7] = (_Float16)hi.w;
    return r;
}

// LDS-only barrier (no vmcnt drain -> x prefetch stays in flight)
__device__ __forceinline__ void sync_lds() {
    asm volatile("s_waitcnt lgkmcnt(0)" ::: "memory");
    __builtin_amdgcn_s_barrier();
    asm volatile("" ::: "memory");
}

// Pin an f16x8 into VGPRs (opaque origin -> no remat/reload in the loop)
#define PIN8(f) do { uint4 _u = __builtin_bit_cast(uint4, (f));              \
    asm volatile("" : "+v"(_u.x), "+v"(_u.y), "+v"(_u.z), "+v"(_u.w));       \
    (f) = __builtin_bit_cast(f16x8, _u); } while (0)

// 12 waves per block = 3 layers x 4 m-quarters; 16 batch columns per block.
// wid = lay*4 + q => SIMD (wid&3) = q hosts exactly {L0,L1,L2}: balanced
// 3 waves/SIMD (R20: 1535->1249 us). 84KB LDS pad forces 1 block/CU so the
// allocator targets 3 waves/EU (avoids R16-R18 spill).
// R23 = R20 byte-identical (AoS handoff, conflicts absorbed -- R22 proved
// conflict-free SoA is neutral) + s_setprio(1) around each wave's
// {handoff-read + MFMA} cluster (T5): SIMDs host role-diverse {L0,L1,L2}
// waves -> scheduler can favor the wave whose operands just landed.
// Skew {L0: t=n | L1: t=n-1 | L2: t=n-2}; 3-slot rotation (write n, read
// n+1, rewrite n+3); one lgkm-only barrier per interval.
// MFMA layout (verified R6): lane l, tile m holds i,f,g,o of unit 8*(l>>4)+m
// for batch l&15; element e of lane's B-frag = h of unit 8*(l>>4)+e; wave q
// contributes dword q (elements 2q,2q+1) of each lane's 16B fragment slot.
__global__ __launch_bounds__(768, 1)
void lstm3_ws12p_kernel(const float* __restrict__ x,
                        const float* __restrict__ Wih0, const float* __restrict__ Whh0,
                        const float* __restrict__ bih0, const float* __restrict__ bhh0,
                        const float* __restrict__ Wih1, const float* __restrict__ Whh1,
                        const float* __restrict__ bih1, const float* __restrict__ bhh1,
                        const float* __restrict__ Wih2, const float* __restrict__ Whh2,
                        const float* __restrict__ bih2, const float* __restrict__ bhh2,
                        const float* __restrict__ Wfc,  const float* __restrict__ bfc,
                        float* __restrict__ out)
{
    const int tid = threadIdx.x;
    const int wid = tid >> 6;         // 0..11
    const int lay = wid >> 2;         // layer 0..2
    const int q   = wid & 3;          // m-quarter == SIMD id
    const int l   = tid & 63;
    const int g   = l >> 4;           // lane group (k-chunk / C row-group)
    const int b   = l & 15;           // batch column
    const int qa  = l & 3;            // gate index for A-row loads
    const int gp  = (l & 15) >> 2;    // unit group for A-row loads
    const int b0  = blockIdx.x * 16;
    const int m0  = q * 2;            // this wave's m-tile base

    __shared__ __align__(16) f16x8 hH[3][3][64];   // [slot][layer][lane]
    __shared__ float FCpart[3][3][16];             // [slot][quarter 0..2][col]
    __shared__ char  pad[86016];                   // forces 1 block/CU

    // ---- weight fragments -> registers (pinned) ----
    f16x8 Fi[2], Fh[2];
    {
        const int rowA = qa * 32 + 8 * gp + m0;
        const float* Pi = (lay == 1) ? Wih1 : ((lay == 2) ? Wih2 : nullptr);
        const float* Ph = (lay == 0) ? Whh0 : ((lay == 1) ? Whh1 : Whh2);
#pragma unroll
        for (int mm = 0; mm < 2; ++mm) {
            Fh[mm] = loadrow8(Ph + (rowA + mm) * 32 + 8 * g);
            PIN8(Fh[mm]);
        }
        if (lay != 0) {
#pragma unroll
            for (int mm = 0; mm < 2; ++mm) {
                Fi[mm] = loadrow8(Pi + (rowA + mm) * 32 + 8 * g);
                PIN8(Fi[mm]);
            }
        }
    }

    // ---- biases / Wih0 / Wfc -> registers (pre-scaled by +/-log2e) ----
    float4 bs[2], w0s[2];
    float wfc_r[2];
    {
        const float* BI = (lay == 0) ? bih0 : ((lay == 1) ? bih1 : bih2);
        const float* BH = (lay == 0) ? bhh0 : ((lay == 1) ? bhh1 : bhh2);
#pragma unroll
        for (int mm = 0; mm < 2; ++mm) {
            const int u = 8 * g + m0 + mm;
            const float bx = BI[u]      + BH[u];
            const float by = BI[u + 32] + BH[u + 32];
            const float bz = BI[u + 64] + BH[u + 64];
            const float bw = BI[u + 96] + BH[u + 96];
            bs[mm] = make_float4(-L2E * bx, -L2E * by, 2.f * L2E * bz, -L2E * bw);
            if (lay == 0)
                w0s[mm] = make_float4(-L2E * Wih0[u],          -L2E * Wih0[u + 32],
                                      2.f * L2E * Wih0[u + 64], -L2E * Wih0[u + 96]);
            if (lay == 2) wfc_r[mm] = Wfc[u];
        }
    }
    const float bfc0 = bfc[0];

    // keep pad alive (runtime-false; bfc0 is ~uniform(-s,s), never 1e30)
    if (bfc0 == 1e30f) { pad[tid] = 1; out[0] = pad[0]; }

    if (q == 0) {                     // zero all slots of own layer
        f16x8 zz = {0, 0, 0, 0, 0, 0, 0, 0};
        hH[0][lay][l] = zz; hH[1][lay][l] = zz; hH[2][lay][l] = zz;
    }
    if (lay == 2 && q == 0 && l < 16) {
        FCpart[0][0][l] = 0.f; FCpart[0][1][l] = 0.f; FCpart[0][2][l] = 0.f;
        FCpart[1][0][l] = 0.f; FCpart[1][1][l] = 0.f; FCpart[1][2][l] = 0.f;
        FCpart[2][0][l] = 0.f; FCpart[2][1][l] = 0.f; FCpart[2][2][l] = 0.f;
    }
    __syncthreads();

    float cst[2] = {0.f, 0.f};
    float vprev = 0.f;                // L2 q3: own FC partial, 1-iv delayed
    float xv = (lay == 0) ? x[b0 + b] : 0.f;

    // fused-rcp LSTM step on 2 m-tiles: acc[2] -> cst, hn[2]
#define ACT2(USE_X, XV)                                                      \
    do {                                                                     \
        _Pragma("unroll")                                                    \
        for (int mm = 0; mm < 2; ++mm) {                                     \
            float ti = fmaf(-L2E,      acc[mm][0], bs[mm].x);                \
            float tf = fmaf(-L2E,      acc[mm][1], bs[mm].y);                \
            float tg = fmaf(2.f * L2E, acc[mm][2], bs[mm].z);                \
            float to = fmaf(-L2E,      acc[mm][3], bs[mm].w);                \
            if (USE_X) {                                                     \
                ti = fmaf(w0s[mm].x, (XV), ti);                              \
                tf = fmaf(w0s[mm].y, (XV), tf);                              \
                tg = fmaf(w0s[mm].z, (XV), tg);                              \
                to = fmaf(w0s[mm].w, (XV), to);                              \
            }                                                                \
            const float ei = __builtin_amdgcn_exp2f(ti);                     \
            const float ef = __builtin_amdgcn_exp2f(tf);                     \
            const float eg = __builtin_amdgcn_exp2f(tg);                     \
            const float eo = __builtin_amdgcn_exp2f(to);                     \
            const float ig = (eg - 1.f) *                                    \
                __builtin_amdgcn_rcpf((1.f + ei) * (1.f + eg));              \
            const float ff = __builtin_amdgcn_rcpf(1.f + ef);                \
            cst[mm] = fmaf(ff, cst[mm], ig);                                 \
            const float tc = fminf(2.f * L2E * cst[mm], 60.f);               \
            const float ec = __builtin_amdgcn_exp2f(tc);                     \
            hn[mm] = (ec - 1.f) *                                            \
                __builtin_amdgcn_rcpf((1.f + eo) * (1.f + ec));              \
        }                                                                    \
    } while (0)

    const int NIT = T_STEPS + 3;      // 2051
    int sw = 0, sp = 2;               // write slot n%3, read slot (n-1)%3
    for (int n = 0; n < NIT; ++n) {
        f32x4 acc[2];
        float hn[2];
        if (lay == 0) {
            // ========== L0(t=n): gates = Whh0 @ h0(n-1) + Wih0*x + b ======
            if (n < T_STEPS) {
                const int tn = (n + 1 < T_STEPS) ? n + 1 : T_STEPS - 1;
                const float xn = x[tn * NBATCH + b0 + b];   // prefetch
                __builtin_amdgcn_s_setprio(1);
                const f16x8 hb0 = hH[sp][0][l];
#pragma unroll
                for (int mm = 0; mm < 2; ++mm) {
                    f32x4 z = {0.f, 0.f, 0.f, 0.f};
                    acc[mm] = __builtin_amdgcn_mfma_f32_16x16x32_f16(Fh[mm], hb0, z, 0, 0, 0);
                }
                __builtin_amdgcn_s_setprio(0);
                ACT2(1, xv);
                reinterpret_cast<unsigned*>(&hH[sw][0][l])[q] = pk2(hn[0], hn[1]);
                xv = xn;
            }
        } else if (lay == 1) {
            // ====== L1(t=n-1): gates = Wih1 @ h0(n-1) + Whh1 @ h1(n-2) ====
            if (n >= 1 && n <= T_STEPS) {
                __builtin_amdgcn_s_setprio(1);
                const f16x8 hb0 = hH[sp][0][l];
                const f16x8 hb1 = hH[sp][1][l];
#pragma unroll
                for (int mm = 0; mm < 2; ++mm) {
                    f32x4 z = {0.f, 0.f, 0.f, 0.f};
                    z       = __builtin_amdgcn_mfma_f32_16x16x32_f16(Fi[mm], hb0, z, 0, 0, 0);
                    acc[mm] = __builtin_amdgcn_mfma_f32_16x16x32_f16(Fh[mm], hb1, z, 0, 0, 0);
                }
                __builtin_amdgcn_s_setprio(0);
                ACT2(0, 0.f);
                reinterpret_cast<unsigned*>(&hH[sw][1][l])[q] = pk2(hn[0], hn[1]);
            }
        } else {
            // == L2(t=n-2): gates = Wih2 @ h1(n-2) + Whh2 @ h2(n-3); FC ====
            // q3 first: store out[t=n-3] from FCpart(n-1) + vprev(n-1)
            if (q == 3 && n >= 3 && l < 16)
                out[(n - 3) * NBATCH + b0 + l] =
                    FCpart[sp][0][l] + FCpart[sp][1][l] + FCpart[sp][2][l]
                    + vprev + bfc0;
            if (n >= 2 && n <= T_STEPS + 1) {
                __builtin_amdgcn_s_setprio(1);
                const f16x8 hb1 = hH[sp][1][l];
                const f16x8 hb2 = hH[sp][2][l];
#pragma unroll
                for (int mm = 0; mm < 2; ++mm) {
                    f32x4 z = {0.f, 0.f, 0.f, 0.f};
                    z       = __builtin_amdgcn_mfma_f32_16x16x32_f16(Fi[mm], hb1, z, 0, 0, 0);
                    acc[mm] = __builtin_amdgcn_mfma_f32_16x16x32_f16(Fh[mm], hb2, z, 0, 0, 0);
                }
                __builtin_amdgcn_s_setprio(0);
                ACT2(0, 0.f);
                reinterpret_cast<unsigned*>(&hH[sw][2][l])[q] = pk2(hn[0], hn[1]);
                float v = fmaf(wfc_r[0], hn[0], wfc_r[1] * hn[1]);
                v += __shfl_xor(v, 16);
                v += __shfl_xor(v, 32);
                if (q < 3) { if (l < 16) FCpart[sw][q][l] = v; }
                else       { vprev = v; }
            }
        }

        sync_lds();                   // reads of slot sp complete (lgkmcnt);
                                      // slot sp is rewritten 2 barriers later
        sp = sw; sw = (sw == 2) ? 0 : sw + 1;
    }
#undef ACT2
}

extern "C" void kernel_launch(void* const* d_in, const int* in_sizes, int n_in,
                              void* d_out, int out_size, void* d_ws, size_t ws_size,
                              hipStream_t stream)
{
    const float* x    = (const float*)d_in[0];
    const float* Wih0 = (const float*)d_in[1];
    const float* Whh0 = (const float*)d_in[2];
    const float* bih0 = (const float*)d_in[3];
    const float* bhh0 = (const float*)d_in[4];
    const float* Wih1 = (const float*)d_in[5];
    const float* Whh1 = (const float*)d_in[6];
    const float* bih1 = (const float*)d_in[7];
    const float* bhh1 = (const float*)d_in[8];
    const float* Wih2 = (const float*)d_in[9];
    const float* Whh2 = (const float*)d_in[10];
    const float* bih2 = (const float*)d_in[11];
    const float* bhh2 = (const float*)d_in[12];
    const float* Wfc  = (const float*)d_in[13];
    const float* bfc  = (const float*)d_in[14];
    float* out        = (float*)d_out;

    lstm3_ws12p_kernel<<<dim3(NBATCH / 16), dim3(768), 0, stream>>>(
        x, Wih0, Whh0, bih0, bhh0,
        Wih1, Whh1, bih1, bhh1,
        Wih2, Whh2, bih2, bhh2,
        Wfc, bfc, out);
}

// Round 24
// 1247.891 us; speedup vs baseline: 1.0439x; 1.0439x over previous
//
#include <hip/hip_runtime.h>

#define T_STEPS 2048
#define NBATCH  1024
#define L2E     1.442695040888963f

typedef _Float16 f16x8 __attribute__((ext_vector_type(8)));
typedef float    f32x4 __attribute__((ext_vector_type(4)));

// pack 2 floats -> 2 fp16 (RTZ) as one u32
__device__ __forceinline__ unsigned pk2(float a, float b) {
    auto v = __builtin_amdgcn_cvt_pkrtz(a, b);
    return __builtin_bit_cast(unsigned, v);
}

// load 8 consecutive fp32 -> 8 fp16 (RNE) fragment
__device__ __forceinline__ f16x8 loadrow8(const float* p) {
    float4 lo = *reinterpret_cast<const float4*>(p);
    float4 hi = *reinterpret_cast<const float4*>(p + 4);
    f16x8 r;
    r[0] = (_Float16)lo.x; r[1] = (_Float16)lo.y;
    r[2] = (_Float16)lo.z; r[3] = (_Float16)lo.w;
    r[4] = (_Float16)hi.x; r[5] = (_Float16)hi.y;
    r[6] = (_Float16)hi.z; r[7] = (_Float16)hi.w;
    return r;
}

// LDS-only barrier (no vmcnt drain -> x prefetch stays in flight)
__device__ __forceinline__ void sync_lds() {
    asm volatile("s_waitcnt lgkmcnt(0)" ::: "memory");
    __builtin_amdgcn_s_barrier();
    asm volatile("" ::: "memory");
}

// Pin an f16x8 into VGPRs (opaque origin -> no remat/reload in the loop)
#define PIN8(f) do { uint4 _u = __builtin_bit_cast(uint4, (f));              \
    asm volatile("" : "+v"(_u.x), "+v"(_u.y), "+v"(_u.z), "+v"(_u.w));       \
    (f) = __builtin_bit_cast(f16x8, _u); } while (0)

// FINAL FORM (= R20, the measured optimum of the series).
// 12 waves per block = 3 layers x 4 m-quarters; 16 batch columns per block.
// wid = lay*4 + q => SIMD (wid&3) = q hosts exactly {L0,L1,L2}: balanced
// 3 waves/SIMD. 84KB LDS pad forces 1 block/CU so the register allocator
// targets 3 waves/EU (avoids the R16-R18 spill heuristic).
// Skew {L0: t=n | L1: t=n-1 | L2: t=n-2}; h handoff via 3-slot rotating LDS
// (write n, read n+1, rewrite n+3); one lgkm-only barrier per interval.
// Weights pinned in registers; biases pre-scaled by +/-log2e; fused-rcp
// activations (3 rcp + 5 exp2 per unit); FC fused via FCpart pipeline.
// Scheduling-lever results (all null/negative vs this base): SoA handoff
// (R22 -3.5%), deep-skew pre-reads (R21 -5.5%), s_setprio (R23 -4%),
// staged SoA acts (R15 0%), 2-step intervals (R13 +4.5% on worse base,
// topologically impossible here). Plateau cause: barrier-aligned waves
// share ds_read-latency and trans-chain phases; ~800 cyc/interval of
// correlated stall is structural to the 1-barrier/step recurrence.
// MFMA layout (verified R6): lane l, tile m holds i,f,g,o of unit 8*(l>>4)+m
// for batch l&15; element e of lane's B-frag = h of unit 8*(l>>4)+e; wave q
// contributes dword q (elements 2q,2q+1) of each lane's 16B fragment slot.
__global__ __launch_bounds__(768, 1)
void lstm3_ws12q_kernel(const float* __restrict__ x,
                        const float* __restrict__ Wih0, const float* __restrict__ Whh0,
                        const float* __restrict__ bih0, const float* __restrict__ bhh0,
                        const float* __restrict__ Wih1, const float* __restrict__ Whh1,
                        const float* __restrict__ bih1, const float* __restrict__ bhh1,
                        const float* __restrict__ Wih2, const float* __restrict__ Whh2,
                        const float* __restrict__ bih2, const float* __restrict__ bhh2,
                        const float* __restrict__ Wfc,  const float* __restrict__ bfc,
                        float* __restrict__ out)
{
    const int tid = threadIdx.x;
    const int wid = tid >> 6;         // 0..11
    const int lay = wid >> 2;         // layer 0..2
    const int q   = wid & 3;          // m-quarter == SIMD id
    const int l   = tid & 63;
    const int g   = l >> 4;           // lane group (k-chunk / C row-group)
    const int b   = l & 15;           // batch column
    const int qa  = l & 3;            // gate index for A-row loads
    const int gp  = (l & 15) >> 2;    // unit group for A-row loads
    const int b0  = blockIdx.x * 16;
    const int m0  = q * 2;            // this wave's m-tile base

    __shared__ __align__(16) f16x8 hH[3][3][64];   // [slot][layer][lane]
    __shared__ float FCpart[3][3][16];             // [slot][quarter 0..2][col]
    __shared__ char  pad[86016];                   // forces 1 block/CU

    // ---- weight fragments -> registers (pinned) ----
    f16x8 Fi[2], Fh[2];
    {
        const int rowA = qa * 32 + 8 * gp + m0;
        const float* Pi = (lay == 1) ? Wih1 : ((lay == 2) ? Wih2 : nullptr);
        const float* Ph = (lay == 0) ? Whh0 : ((lay == 1) ? Whh1 : Whh2);
#pragma unroll
        for (int mm = 0; mm < 2; ++mm) {
            Fh[mm] = loadrow8(Ph + (rowA + mm) * 32 + 8 * g);
            PIN8(Fh[mm]);
        }
        if (lay != 0) {
#pragma unroll
            for (int mm = 0; mm < 2; ++mm) {
                Fi[mm] = loadrow8(Pi + (rowA + mm) * 32 + 8 * g);
                PIN8(Fi[mm]);
            }
        }
    }

    // ---- biases / Wih0 / Wfc -> registers (pre-scaled by +/-log2e) ----
    float4 bs[2], w0s[2];
    float wfc_r[2];
    {
        const float* BI = (lay == 0) ? bih0 : ((lay == 1) ? bih1 : bih2);
        const float* BH = (lay == 0) ? bhh0 : ((lay == 1) ? bhh1 : bhh2);
#pragma unroll
        for (int mm = 0; mm < 2; ++mm) {
            const int u = 8 * g + m0 + mm;
            const float bx = BI[u]      + BH[u];
            const float by = BI[u + 32] + BH[u + 32];
            const float bz = BI[u + 64] + BH[u + 64];
            const float bw = BI[u + 96] + BH[u + 96];
            bs[mm] = make_float4(-L2E * bx, -L2E * by, 2.f * L2E * bz, -L2E * bw);
            if (lay == 0)
                w0s[mm] = make_float4(-L2E * Wih0[u],          -L2E * Wih0[u + 32],
                                      2.f * L2E * Wih0[u + 64], -L2E * Wih0[u + 96]);
            if (lay == 2) wfc_r[mm] = Wfc[u];
        }
    }
    const float bfc0 = bfc[0];

    // keep pad alive (runtime-false; bfc0 is ~uniform(-s,s), never 1e30)
    if (bfc0 == 1e30f) { pad[tid] = 1; out[0] = pad[0]; }

    if (q == 0) {                     // zero all slots of own layer
        f16x8 zz = {0, 0, 0, 0, 0, 0, 0, 0};
        hH[0][lay][l] = zz; hH[1][lay][l] = zz; hH[2][lay][l] = zz;
    }
    if (lay == 2 && q == 0 && l < 16) {
        FCpart[0][0][l] = 0.f; FCpart[0][1][l] = 0.f; FCpart[0][2][l] = 0.f;
        FCpart[1][0][l] = 0.f; FCpart[1][1][l] = 0.f; FCpart[1][2][l] = 0.f;
        FCpart[2][0][l] = 0.f; FCpart[2][1][l] = 0.f; FCpart[2][2][l] = 0.f;
    }
    __syncthreads();

    float cst[2] = {0.f, 0.f};
    float vprev = 0.f;                // L2 q3: own FC partial, 1-iv delayed
    float xv = (lay == 0) ? x[b0 + b] : 0.f;

    // fused-rcp LSTM step on 2 m-tiles: acc[2] -> cst, hn[2]
#define ACT2(USE_X, XV)                                                      \
    do {                                                                     \
        _Pragma("unroll")                                                    \
        for (int mm = 0; mm < 2; ++mm) {                                     \
            float ti = fmaf(-L2E,      acc[mm][0], bs[mm].x);                \
            float tf = fmaf(-L2E,      acc[mm][1], bs[mm].y);                \
            float tg = fmaf(2.f * L2E, acc[mm][2], bs[mm].z);                \
            float to = fmaf(-L2E,      acc[mm][3], bs[mm].w);                \
            if (USE_X) {                                                     \
                ti = fmaf(w0s[mm].x, (XV), ti);                              \
                tf = fmaf(w0s[mm].y, (XV), tf);                              \
                tg = fmaf(w0s[mm].z, (XV), tg);                              \
                to = fmaf(w0s[mm].w, (XV), to);                              \
            }                                                                \
            const float ei = __builtin_amdgcn_exp2f(ti);                     \
            const float ef = __builtin_amdgcn_exp2f(tf);                     \
            const float eg = __builtin_amdgcn_exp2f(tg);                     \
            const float eo = __builtin_amdgcn_exp2f(to);                     \
            const float ig = (eg - 1.f) *                                    \
                __builtin_amdgcn_rcpf((1.f + ei) * (1.f + eg));              \
            const float ff = __builtin_amdgcn_rcpf(1.f + ef);                \
            cst[mm] = fmaf(ff, cst[mm], ig);                                 \
            const float tc = fminf(2.f * L2E * cst[mm], 60.f);               \
            const float ec = __builtin_amdgcn_exp2f(tc);                     \
            hn[mm] = (ec - 1.f) *                                            \
                __builtin_amdgcn_rcpf((1.f + eo) * (1.f + ec));              \
        }                                                                    \
    } while (0)

    const int NIT = T_STEPS + 3;      // 2051
    int sw = 0, sp = 2;               // write slot n%3, read slot (n-1)%3
    for (int n = 0; n < NIT; ++n) {
        f32x4 acc[2];
        float hn[2];
        if (lay == 0) {
            // ========== L0(t=n): gates = Whh0 @ h0(n-1) + Wih0*x + b ======
            if (n < T_STEPS) {
                const int tn = (n + 1 < T_STEPS) ? n + 1 : T_STEPS - 1;
                const float xn = x[tn * NBATCH + b0 + b];   // prefetch
                const f16x8 hb0 = hH[sp][0][l];
#pragma unroll
                for (int mm = 0; mm < 2; ++mm) {
                    f32x4 z = {0.f, 0.f, 0.f, 0.f};
                    acc[mm] = __builtin_amdgcn_mfma_f32_16x16x32_f16(Fh[mm], hb0, z, 0, 0, 0);
                }
                ACT2(1, xv);
                reinterpret_cast<unsigned*>(&hH[sw][0][l])[q] = pk2(hn[0], hn[1]);
                xv = xn;
            }
        } else if (lay == 1) {
            // ====== L1(t=n-1): gates = Wih1 @ h0(n-1) + Whh1 @ h1(n-2) ====
            if (n >= 1 && n <= T_STEPS) {
                const f16x8 hb0 = hH[sp][0][l];
                const f16x8 hb1 = hH[sp][1][l];
#pragma unroll
                for (int mm = 0; mm < 2; ++mm) {
                    f32x4 z = {0.f, 0.f, 0.f, 0.f};
                    z       = __builtin_amdgcn_mfma_f32_16x16x32_f16(Fi[mm], hb0, z, 0, 0, 0);
                    acc[mm] = __builtin_amdgcn_mfma_f32_16x16x32_f16(Fh[mm], hb1, z, 0, 0, 0);
                }
                ACT2(0, 0.f);
                reinterpret_cast<unsigned*>(&hH[sw][1][l])[q] = pk2(hn[0], hn[1]);
            }
        } else {
            // == L2(t=n-2): gates = Wih2 @ h1(n-2) + Whh2 @ h2(n-3); FC ====
            // q3 first: store out[t=n-3] from FCpart(n-1) + vprev(n-1)
            if (q == 3 && n >= 3 && l < 16)
                out[(n - 3) * NBATCH + b0 + l] =
                    FCpart[sp][0][l] + FCpart[sp][1][l] + FCpart[sp][2][l]
                    + vprev + bfc0;
            if (n >= 2 && n <= T_STEPS + 1) {
                const f16x8 hb1 = hH[sp][1][l];
                const f16x8 hb2 = hH[sp][2][l];
#pragma unroll
                for (int mm = 0; mm < 2; ++mm) {
                    f32x4 z = {0.f, 0.f, 0.f, 0.f};
                    z       = __builtin_amdgcn_mfma_f32_16x16x32_f16(Fi[mm], hb1, z, 0, 0, 0);
                    acc[mm] = __builtin_amdgcn_mfma_f32_16x16x32_f16(Fh[mm], hb2, z, 0, 0, 0);
                }
                ACT2(0, 0.f);
                reinterpret_cast<unsigned*>(&hH[sw][2][l])[q] = pk2(hn[0], hn[1]);
                float v = fmaf(wfc_r[0], hn[0], wfc_r[1] * hn[1]);
                v += __shfl_xor(v, 16);
                v += __shfl_xor(v, 32);
                if (q < 3) { if (l < 16) FCpart[sw][q][l] = v; }
                else       { vprev = v; }
            }
        }

        sync_lds();                   // reads of slot sp complete (lgkmcnt);
                                      // slot sp is rewritten 2 barriers later
        sp = sw; sw = (sw == 2) ? 0 : sw + 1;
    }
#undef ACT2
}

extern "C" void kernel_launch(void* const* d_in, const int* in_sizes, int n_in,
                              void* d_out, int out_size, void* d_ws, size_t ws_size,
                              hipStream_t stream)
{
    const float* x    = (const float*)d_in[0];
    const float* Wih0 = (const float*)d_in[1];
    const float* Whh0 = (const float*)d_in[2];
    const float* bih0 = (const float*)d_in[3];
    const float* bhh0 = (const float*)d_in[4];
    const float* Wih1 = (const float*)d_in[5];
    const float* Whh1 = (const float*)d_in[6];
    const float* bih1 = (const float*)d_in[7];
    const float* bhh1 = (const float*)d_in[8];
    const float* Wih2 = (const float*)d_in[9];
    const float* Whh2 = (const float*)d_in[10];
    const float* bih2 = (const float*)d_in[11];
    const float* bhh2 = (const float*)d_in[12];
    const float* Wfc  = (const float*)d_in[13];
    const float* bfc  = (const float*)d_in[14];
    float* out        = (float*)d_out;

    lstm3_ws12q_kernel<<<dim3(NBATCH / 16), dim3(768), 0, stream>>>(
        x, Wih0, Whh0, bih0, bhh0,
        Wih1, Whh1, bih1, bhh1,
        Wih2, Whh2, bih2, bhh2,
        Wfc, bfc, out);
}